// Round 15
// baseline (193.084 us; speedup 1.0000x reference)
//
#include <hip/hip_runtime.h>
#include <math.h>

namespace {

constexpr int kH = 500, kW = 500, kNV = 5023, kNF = 9976, kB = 2;
constexpr float kFocal = 1015.0f;
constexpr float kEps = 1e-6f;
constexpr int kNB = 8;                       // z buckets per tile
constexpr int kChunks = 8;                   // face chunks (binning blocks)
constexpr int kFPC = kNF / kChunks;          // 1247 faces per chunk
constexpr int kSplit = 2;                    // raster blocks per tile
constexpr unsigned kListCap = 1800000u;      // u16 entries

// ---------------------------------------------------------------- utilities
__device__ inline void cross3(float ax, float ay, float az,
                              float bx, float by, float bz,
                              float& cx, float& cy, float& cz) {
  cx = ay * bz - az * by;
  cy = az * bx - ax * bz;
  cz = ax * by - ay * bx;
}

// Edge-separation triangle-vs-tile cull. Bit-identical between count and fill
// passes (same fn, same inputs -> deterministic counts).
__device__ inline bool tileCull(const float4 r0, const float4 r1,
                                float tX0, float tX1, float tY0, float tY1) {
  float hi0 = fmaf(r0.x, r0.x >= 0.f ? tX1 : tX0,
                   fmaf(r0.y, r0.y >= 0.f ? tY1 : tY0, r0.z));
  float lo0 = fmaf(r0.x, r0.x >= 0.f ? tX0 : tX1,
                   fmaf(r0.y, r0.y >= 0.f ? tY0 : tY1, r0.z));
  float hi1 = fmaf(r1.x, r1.x >= 0.f ? tX1 : tX0,
                   fmaf(r1.y, r1.y >= 0.f ? tY1 : tY0, r1.z));
  float lo1 = fmaf(r1.x, r1.x >= 0.f ? tX0 : tX1,
                   fmaf(r1.y, r1.y >= 0.f ? tY0 : tY1, r1.z));
  float m2 = 2.f * r0.w;   // looser than the per-pixel margin -mw: conservative
  return hi0 >= -m2 && hi1 >= -m2 && (1.f - lo0 - lo1) >= -m2;
}

__device__ inline int bucketOf(float zminf, float zlo, float iscale) {
  float t = (zminf - zlo) * iscale;
  t = fminf(fmaxf(t, 0.f), (float)(kNB - 1));
  return (int)t;
}

// Exact reference projection (feeds discrete decisions -> _rn, no FMA).
__device__ inline void projectV(const float* __restrict__ vb, int vi,
                                float& px, float& py, float& zc) {
  float vx = vb[3 * vi], vy = vb[3 * vi + 1], vz = vb[3 * vi + 2];
  float xc = -vx, yc = vy;
  zc = -vz;
  float zs = fmaxf(zc, kEps);
  px = __fsub_rn(0.5f * kW, __fdiv_rn(__fmul_rn(kFocal, xc), zs));
  py = __fsub_rn(0.5f * kH, __fdiv_rn(__fmul_rn(kFocal, yc), zs));
}

// ---------------------------------------------------------------- kernels
// FUSED per-(b,f): normal scatter-accumulation (nacc pre-zeroed by memset)
// + face setup with inline exact _rn projection. zr: [0..1]=min (0xFF init),
// [2..3]=max (0 init), [4]=list cursor (0 init).
__global__ void setup_k(const float* __restrict__ verts,
                        const int* __restrict__ faces,
                        float* __restrict__ nacc,
                        float4* __restrict__ fdE,
                        float4* __restrict__ fdP,
                        unsigned* __restrict__ tb,
                        unsigned* __restrict__ zr) {
  int f = blockIdx.x * 256 + threadIdx.x;
  int b = blockIdx.y;
  bool act = (f < kNF);
  float redMin = INFINITY, redMax = 0.0f;   // neutral for inactive/invalid
  if (act) {
    size_t idx = (size_t)b * kNF + f;
    const float* vb = verts + (size_t)b * kNV * 3;
    int i0 = faces[3 * f + 0], i1 = faces[3 * f + 1], i2 = faces[3 * f + 2];
    // ---- normal scatter (raw world-space verts) ----
    {
      float x0 = vb[3 * i0], y0 = vb[3 * i0 + 1], z0 = vb[3 * i0 + 2];
      float x1 = vb[3 * i1], y1 = vb[3 * i1 + 1], z1 = vb[3 * i1 + 2];
      float x2 = vb[3 * i2], y2 = vb[3 * i2 + 1], z2 = vb[3 * i2 + 2];
      float* nb = nacc + (size_t)b * kNV * 3;
      float cx, cy, cz;
      cross3(x2 - x1, y2 - y1, z2 - z1, x0 - x1, y0 - y1, z0 - z1, cx, cy, cz);
      atomicAdd(nb + 3 * i1 + 0, cx);
      atomicAdd(nb + 3 * i1 + 1, cy);
      atomicAdd(nb + 3 * i1 + 2, cz);
      cross3(x0 - x2, y0 - y2, z0 - z2, x1 - x2, y1 - y2, z1 - z2, cx, cy, cz);
      atomicAdd(nb + 3 * i2 + 0, cx);
      atomicAdd(nb + 3 * i2 + 1, cy);
      atomicAdd(nb + 3 * i2 + 2, cz);
      cross3(x1 - x0, y1 - y0, z1 - z0, x2 - x0, y2 - y0, z2 - z0, cx, cy, cz);
      atomicAdd(nb + 3 * i0 + 0, cx);
      atomicAdd(nb + 3 * i0 + 1, cy);
      atomicAdd(nb + 3 * i0 + 2, cz);
    }
    // ---- face setup ----
    float ax, ay, za, bx, by, zb, cx, cy, zc;
    projectV(vb, i0, ax, ay, za);
    projectV(vb, i1, bx, by, zb);
    projectV(vb, i2, cx, cy, zc);
    float A0 = __fsub_rn(by, cy);
    float B0 = __fsub_rn(cx, bx);
    float A1 = __fsub_rn(cy, ay);
    float B1 = __fsub_rn(ax, cx);
    float e = __fsub_rn(ay, cy);
    float den = __fadd_rn(__fmul_rn(A0, B1), __fmul_rn(B0, e));
    bool valid =
        (fabsf(den) >= kEps) && (za > kEps) && (zb > kEps) && (zc > kEps);
    float ds = valid ? den : 1.0f;

    float4* oe = fdE + idx * 3;
    oe[0] = make_float4(cx, cy, A0, B0);
    oe[1] = make_float4(A1, B1, ds, za);
    oe[2] = make_float4(zb, zc, 0.0f, 0.0f);

    float P0 = A0 / ds, Q0 = B0 / ds, R0 = -(A0 * cx + B0 * cy) / ds;
    float P1 = A1 / ds, Q1 = B1 / ds, R1 = -(A1 * cx + B1 * cy) / ds;
    float dza = za - zc, dzb = zb - zc;
    float Zx = dza * P0 + dzb * P1;
    float Zy = dza * Q0 + dzb * Q1;
    float Zc = dza * R0 + dzb * R1 + zc;
    float S0 = (fabsf(P0) + fabsf(Q0)) * 512.f + fabsf(R0);
    float S1 = (fabsf(P1) + fabsf(Q1)) * 512.f + fabsf(R1);
    float Sz = (fabsf(Zx) + fabsf(Zy)) * 512.f + fabsf(Zc);
    float m0 = S0 * 0x1p-18f;
    float m1 = S1 * 0x1p-18f;
    float mw = m0 + m1 + 2e-6f;
    float mz = m0 * fabsf(dza) + m1 * fabsf(dzb) + Sz * 0x1p-18f +
               0x1p-18f * (fabsf(zc) + fabsf(dza) + fabsf(dzb) + 1.f) + 2e-6f;
    float zminf = fminf(fminf(za, zb), zc);

    float4* op = fdP + idx * 3;
    op[0] = make_float4(P0, Q0, R0, mw);
    op[1] = make_float4(P1, Q1, R1, mz);
    op[2] = make_float4(Zx, Zy, Zc, zminf);

    unsigned pack;
    if (valid) {
      float mnx = fminf(fminf(ax, bx), cx) - 0.5f;
      float mxx = fmaxf(fmaxf(ax, bx), cx) + 0.5f;
      float mny = fminf(fminf(ay, by), cy) - 0.5f;
      float mxy = fmaxf(fmaxf(ay, by), cy) + 0.5f;
      float c0 = fminf(fmaxf(ceilf((mnx - 15.5f) * 0.0625f), 0.f), 31.f);
      float c1 = fminf(fmaxf(floorf((mxx - 0.5f) * 0.0625f), 0.f), 31.f);
      float r0 = fminf(fmaxf(ceilf((mny - 15.5f) * 0.0625f), 0.f), 31.f);
      float r1 = fminf(fmaxf(floorf((mxy - 0.5f) * 0.0625f), 0.f), 31.f);
      unsigned uc0 = (unsigned)c0, uc1 = (unsigned)c1;
      unsigned ur0 = (unsigned)r0, ur1 = (unsigned)r1;
      if (mxx < mnx || mxy < mny) { uc0 = 1; uc1 = 0; }   // degenerate guard
      pack = uc0 | (uc1 << 8) | (ur0 << 16) | (ur1 << 24);
      redMin = zminf;   // zminf > eps > 0 -> uint bit-order == float order
      redMax = zminf;
    } else {
      pack = 1u;   // cxlo=1 > cxhi=0 -> empty
    }
    tb[idx] = pack;
  }
  // Wave-level z-range butterfly -> one atomic per wave (R3 lesson).
#pragma unroll
  for (int d = 32; d >= 1; d >>= 1) {
    redMin = fminf(redMin, __shfl_xor(redMin, d, 64));
    redMax = fmaxf(redMax, __shfl_xor(redMax, d, 64));
  }
  if ((threadIdx.x & 63) == 0 && redMin < INFINITY) {
    atomicMin(zr + b, __float_as_uint(redMin));        // zrMin
    atomicMax(zr + 2 + b, __float_as_uint(redMax));    // zrMax
  }
}

// SINGLE-DISPATCH binning (R13 win): LDS count -> intra-block scan -> ONE
// global cursor atomicAdd claims a contiguous segment -> absolute offsets to
// cnt[block][257] -> identical-cull fill. Segment order racy; per-cell SETS
// deterministic; (z,idx) lex-min order-independent -> deterministic output.
__global__ __launch_bounds__(256) void bin_k(
    const float4* __restrict__ fdP, const unsigned* __restrict__ tb,
    unsigned* __restrict__ zr, unsigned* __restrict__ cnt,
    unsigned short* __restrict__ list) {
  __shared__ unsigned lc[256];
  __shared__ unsigned segBase;
  int c = blockIdx.x, ty = blockIdx.y, b = blockIdx.z;
  size_t bOff = (size_t)b * kNF;
  int t = threadIdx.x;
  lc[t] = 0u;
  __syncthreads();

  float tY0 = 16.f * ty + 0.5f, tY1 = tY0 + 15.f;
  float zlo = __uint_as_float(zr[b]);
  float zhi = __uint_as_float(zr[2 + b]);
  float range = zhi - zlo;
  float iscale = range > 1e-30f ? (float)kNB / range : 0.f;
  int f0 = c * kFPC, f1 = min(kNF, f0 + kFPC);

  for (int f = f0 + t; f < f1; f += 256) {
    unsigned pk = tb[bOff + f];
    int cx0 = pk & 0xFF, cx1 = (pk >> 8) & 0xFF;
    int ry0 = (pk >> 16) & 0xFF, ry1 = (pk >> 24) & 0xFF;
    if (ty < ry0 || ty > ry1 || cx0 > cx1) continue;
    const float4* rp = fdP + (bOff + f) * 3;
    float4 r0 = rp[0], r1 = rp[1], r2 = rp[2];
    int q = bucketOf(r2.w, zlo, iscale);
    for (int tx = cx0; tx <= cx1; ++tx) {
      float tX0 = 16.f * tx + 0.5f, tX1 = tX0 + 15.f;
      if (tileCull(r0, r1, tX0, tX1, tY0, tY1))
        atomicAdd(&lc[tx * kNB + q], 1u);
    }
  }
  __syncthreads();

  unsigned own = lc[t];
  for (int d = 1; d < 256; d <<= 1) {
    unsigned w = (t >= d) ? lc[t - d] : 0u;
    __syncthreads();
    lc[t] += w;
    __syncthreads();
  }
  unsigned excl = lc[t] - own;
  unsigned tot = lc[255];
  if (t == 0) segBase = atomicAdd(&zr[4], tot);
  __syncthreads();
  unsigned sb = segBase;

  unsigned blk = ((unsigned)(b * 32 + ty) * kChunks + (unsigned)c);
  cnt[blk * 257 + t] = sb + excl;
  if (t == 0) cnt[blk * 257 + 256] = sb + tot;
  __syncthreads();
  lc[t] = sb + excl;
  __syncthreads();

  for (int f = f0 + t; f < f1; f += 256) {
    unsigned pk = tb[bOff + f];
    int cx0 = pk & 0xFF, cx1 = (pk >> 8) & 0xFF;
    int ry0 = (pk >> 16) & 0xFF, ry1 = (pk >> 24) & 0xFF;
    if (ty < ry0 || ty > ry1 || cx0 > cx1) continue;
    const float4* rp = fdP + (bOff + f) * 3;
    float4 r0 = rp[0], r1 = rp[1], r2 = rp[2];
    int q = bucketOf(r2.w, zlo, iscale);
    for (int tx = cx0; tx <= cx1; ++tx) {
      float tX0 = 16.f * tx + 0.5f, tX1 = tX0 + 15.f;
      if (tileCull(r0, r1, tX0, tX1, tY0, tY1)) {
        unsigned pos = atomicAdd(&lc[tx * kNB + q], 1u);
        if (pos < kListCap) list[pos] = (unsigned short)f;
      }
    }
  }
}

// Tile raster, SPLIT x2 across blocks (R6 lesson: intra-block splits share
// one CU's SIMDs -> null; cross-BLOCK splits put the heavy tile on 2 CUs).
// grid.z = b*2+s; split s takes strided candidates idx = s + 2j of each
// bucket's concatenated list (front buckets dense -> both splits early-break
// almost as well). Partial (zmin,best) merged via u64 (z,idx) atomicMin
// into d_out's first 8B per pixel (init 0xFF; L2-resident; R2-validated
// pattern) -- order-independent lex-min == jnp.argmin. shade_k finishes.
__global__ __launch_bounds__(256) void raster_k(
    const float4* __restrict__ fdP, const float4* __restrict__ fdE,
    const unsigned* __restrict__ cnt, const unsigned short* __restrict__ list,
    const unsigned* __restrict__ zr, unsigned long long* __restrict__ keys) {
  __shared__ float4 sA[256], sB[256], sC[256];   // 12 KiB stage
  __shared__ unsigned sOff[kChunks * 9];
  int bz = blockIdx.z;
  int b = bz >> 1, s = bz & 1;
  size_t bOff = (size_t)b * kNF;
  int t = threadIdx.x;
  int tx = t & 15, ty = t >> 4;
  int x = blockIdx.x * 16 + tx;
  int y = blockIdx.y * 16 + ty;
  float xp = (float)x + 0.5f;
  float yp = (float)y + 0.5f;
  bool live = (x < kW && y < kH);
  float zmin = live ? INFINITY : -INFINITY;   // dead px never block the break
  int best = 0x7FFFFFFF;

  float zlo = __uint_as_float(zr[b]);
  float zhi = __uint_as_float(zr[2 + b]);
  float range = zhi - zlo;
  float bwid = range > 1e-30f ? range * (1.f / kNB) : 0.f;

  if (t < kChunks * 9) {
    int c = t / 9, j = t - c * 9;
    unsigned blk = ((unsigned)(b * 32 + blockIdx.y) * kChunks + (unsigned)c);
    sOff[t] = cnt[blk * 257 + blockIdx.x * 8 + j];
  }
  __syncthreads();

  for (int q = 0; q < kNB; ++q) {
    if (q > 0) {
      float lb = zlo + (float)q * bwid * (1.f - 1e-5f) - 2e-5f;
      if (__syncthreads_and(zmin < lb)) break;
    }
    unsigned st[kChunks], pre[kChunks + 1];
    pre[0] = 0;
#pragma unroll
    for (int c = 0; c < kChunks; ++c) {
      unsigned s0 = sOff[c * 9 + q], e0 = sOff[c * 9 + q + 1];
      st[c] = s0;
      pre[c + 1] = pre[c] + (e0 - s0);
    }
    unsigned m = pre[kChunks];
    unsigned mS = (m > (unsigned)s) ? (m - s + 1) >> 1 : 0u;   // strided count
    for (unsigned base = 0; base < mS; base += 256) {
      int n = min(256u, mS - base);
      __syncthreads();
      if (t < n) {
        unsigned idx = (base + t) * 2 + s, src = 0;
#pragma unroll
        for (int c = 0; c < kChunks; ++c)
          if (idx >= pre[c] && idx < pre[c + 1]) src = st[c] + (idx - pre[c]);
        unsigned fi = list[src];
        const float4* rp = fdP + (bOff + fi) * 3;
        float4 r0 = rp[0], r1 = rp[1], r2 = rp[2];
        r2.w = __int_as_float((int)fi);
        sA[t] = r0;
        sB[t] = r1;
        sC[t] = r2;
      }
      __syncthreads();
      for (int k = 0; k < n; ++k) {
        float4 a = sA[k], bq = sB[k], c = sC[k];
        float w0a = fmaf(a.x, xp, fmaf(a.y, yp, a.z));
        float w1a = fmaf(bq.x, xp, fmaf(bq.y, yp, bq.z));
        float w2a = 1.f - w0a - w1a;
        float zl = fmaf(c.x, xp, fmaf(c.y, yp, c.z));
        float wmin = fminf(fminf(w0a, w1a), w2a);
        if (wmin >= -a.w && zl <= zmin + bq.w) {
          // Exact path: replicate reference fp32 rounding bit-for-bit.
          int fi = __float_as_int(c.w);
          const float4* ep = fdE + (bOff + fi) * 3;
          float4 e0 = ep[0], e1 = ep[1], e2 = ep[2];
          float dx = __fsub_rn(xp, e0.x), dy = __fsub_rn(yp, e0.y);
          float num0 = __fadd_rn(__fmul_rn(e0.z, dx), __fmul_rn(e0.w, dy));
          float num1 = __fadd_rn(__fmul_rn(e1.x, dx), __fmul_rn(e1.y, dy));
          float w0 = __fdiv_rn(num0, e1.z);
          float w1 = __fdiv_rn(num1, e1.z);
          float w2 = __fsub_rn(__fsub_rn(1.f, w0), w1);
          if (w0 >= 0.f && w1 >= 0.f && w2 >= 0.f) {
            float z = __fadd_rn(
                __fadd_rn(__fmul_rn(w0, e1.w), __fmul_rn(w1, e2.x)),
                __fmul_rn(w2, e2.y));
            if (z < zmin || (z == zmin && fi < best)) { zmin = z; best = fi; }
          }
        }
      }
    }
  }

  if (live && zmin < INFINITY) {
    unsigned long long key =
        ((unsigned long long)__float_as_uint(zmin) << 32) | (unsigned)best;
    atomicMin(&keys[(((size_t)b * kH + y) * kW + x) * 2], key);
  }
}

// Per pixel: decode winner key from d_out, recompute exact barycentrics
// (bit-identical to raster's exact path), shade, overwrite pixel.
__global__ void shade_k(const float4* __restrict__ fdE,
                        const float* __restrict__ verts,
                        const float* __restrict__ nacc,
                        const int* __restrict__ faces,
                        float* __restrict__ out) {
  int p = blockIdx.x * 256 + threadIdx.x;
  if (p >= kB * kH * kW) return;
  int b = p / (kH * kW);
  int r = p - b * kH * kW;
  int y = r / kW, x = r - y * kW;
  unsigned long long key = ((const unsigned long long*)out)[(size_t)p * 2];
  float rv, av;
  if (key == ~0ull) {
    rv = 1.0f; av = 0.0f;
  } else {
    int fi = (int)(key & 0xFFFFFFFFull);
    float xp = (float)x + 0.5f, yp = (float)y + 0.5f;
    const float4* ep = fdE + ((size_t)b * kNF + fi) * 3;
    float4 e0 = ep[0], e1 = ep[1];
    float dx = __fsub_rn(xp, e0.x), dy = __fsub_rn(yp, e0.y);
    float num0 = __fadd_rn(__fmul_rn(e0.z, dx), __fmul_rn(e0.w, dy));
    float num1 = __fadd_rn(__fmul_rn(e1.x, dx), __fmul_rn(e1.y, dy));
    float w0 = __fdiv_rn(num0, e1.z);
    float w1 = __fdiv_rn(num1, e1.z);
    float w2 = __fsub_rn(__fsub_rn(1.f, w0), w1);
    int i0 = faces[3 * fi + 0], i1 = faces[3 * fi + 1], i2 = faces[3 * fi + 2];
    const float* vb = verts + (size_t)b * kNV * 3;
    const float* nb = nacc + (size_t)b * kNV * 3;
    float n0x = nb[3 * i0], n0y = nb[3 * i0 + 1], n0z = nb[3 * i0 + 2];
    float n1x = nb[3 * i1], n1y = nb[3 * i1 + 1], n1z = nb[3 * i1 + 2];
    float n2x = nb[3 * i2], n2y = nb[3 * i2 + 1], n2z = nb[3 * i2 + 2];
    float d0 = fmaxf(sqrtf(n0x * n0x + n0y * n0y + n0z * n0z), kEps);
    float d1 = fmaxf(sqrtf(n1x * n1x + n1y * n1y + n1z * n1z), kEps);
    float d2 = fmaxf(sqrtf(n2x * n2x + n2y * n2y + n2z * n2z), kEps);
    n0x /= d0; n0y /= d0; n0z /= d0;
    n1x /= d1; n1y /= d1; n1z /= d1;
    n2x /= d2; n2y /= d2; n2z /= d2;
    float px_ = w0 * vb[3 * i0 + 0] + w1 * vb[3 * i1 + 0] + w2 * vb[3 * i2 + 0];
    float py_ = w0 * vb[3 * i0 + 1] + w1 * vb[3 * i1 + 1] + w2 * vb[3 * i2 + 1];
    float pz_ = w0 * vb[3 * i0 + 2] + w1 * vb[3 * i1 + 2] + w2 * vb[3 * i2 + 2];
    float nx = w0 * n0x + w1 * n1x + w2 * n2x;
    float ny = w0 * n0y + w1 * n1y + w2 * n2y;
    float nz = w0 * n0z + w1 * n1z + w2 * n2z;
    float nn = sqrtf(nx * nx + ny * ny + nz * nz);
    float nd = fmaxf(nn, kEps);
    nx /= nd; ny /= nd; nz /= nd;
    float pn = sqrtf(px_ * px_ + py_ * py_ + pz_ * pz_);
    float pd = fmaxf(pn, kEps);
    float lx = -px_ / pd, ly = -py_ / pd, lz = -pz_ / pd;
    float sdot = nx * lx + ny * ly + nz * lz;
    float ndl = fmaxf(sdot, 0.0f);
    float rx = 2.0f * sdot * nx - lx;
    float ry = 2.0f * sdot * ny - ly;
    float rz = 2.0f * sdot * nz - lz;
    float vdr = fmaxf(lx * rx + ly * ry + lz * rz, 0.0f);
    float qv = vdr;   // vdr^64 via 6 squarings
    qv = qv * qv; qv = qv * qv; qv = qv * qv;
    qv = qv * qv; qv = qv * qv; qv = qv * qv;
    float shade = 0.5f * (0.5f + 0.3f * ndl) + 0.2f * qv;
    rv = fminf(fmaxf(shade, 0.0f), 255.0f);
    av = 1.0f;
  }
  ((float4*)out)[p] = make_float4(rv, rv, rv, av);
}

}  // namespace

extern "C" void kernel_launch(void* const* d_in, const int* in_sizes, int n_in,
                              void* d_out, int out_size, void* d_ws, size_t ws_size,
                              hipStream_t stream) {
  (void)in_sizes; (void)n_in; (void)out_size; (void)ws_size;
  const float* verts = (const float*)d_in[0];   // (B, NV, 3) f32
  const int* faces = (const int*)d_in[1];       // (NF, 3) i32
  float* out = (float*)d_out;                   // (B, H, W, 4) f32
  float* ws = (float*)d_ws;

  // ws layout (float offsets; total ~6.41 MB <= proven ws >= 6.52 MB):
  //   nacc @ 0          (30,138)
  //   fdE  @ 71,680     (float4 x 59,856)
  //   fdP  @ 311,296    (float4 x 59,856)
  //   tb   @ 550,912    (u32 x 19,952)
  //   zr   @ 570,880    (u32 x 8: [0..1]=min(0xFF) [2..3]=max(0) [4]=cursor(0))
  //   cnt  @ 571,008    (u32 x 512*257)
  //   list @ 702,720    (u16 x 1,800,000)
  float* nacc = ws;
  float4* fdE = (float4*)(ws + 71680);
  float4* fdP = (float4*)(ws + 311296);
  unsigned* tb = (unsigned*)(ws + 550912);
  unsigned* zr = (unsigned*)(ws + 570880);
  unsigned* cnt = (unsigned*)(ws + 571008);
  unsigned short* list = (unsigned short*)(ws + 702720);

  hipMemsetAsync(nacc, 0, (size_t)kB * kNV * 3 * sizeof(float), stream);
  hipMemsetAsync(zr, 0xFF, 2 * sizeof(unsigned), stream);       // zrMin
  hipMemsetAsync(zr + 2, 0x00, 3 * sizeof(unsigned), stream);   // zrMax+cursor
  hipMemsetAsync(out, 0xFF, (size_t)kB * kH * kW * 16, stream); // key sentinel

  hipLaunchKernelGGL(setup_k, dim3((kNF + 255) / 256, kB), dim3(256), 0,
                     stream, verts, faces, nacc, fdE, fdP, tb, zr);
  hipLaunchKernelGGL(bin_k, dim3(kChunks, 32, kB), dim3(256), 0,
                     stream, fdP, tb, zr, cnt, list);
  hipLaunchKernelGGL(raster_k, dim3(32, 32, kB * kSplit), dim3(256), 0, stream,
                     fdP, fdE, cnt, list, zr, (unsigned long long*)out);
  hipLaunchKernelGGL(shade_k, dim3((kB * kH * kW + 255) / 256), dim3(256), 0,
                     stream, fdE, verts, nacc, faces, out);
}

// Round 16
// 190.867 us; speedup vs baseline: 1.0116x; 1.0116x over previous
//
#include <hip/hip_runtime.h>
#include <math.h>

namespace {

constexpr int kH = 500, kW = 500, kNV = 5023, kNF = 9976, kB = 2;
constexpr float kFocal = 1015.0f;
constexpr float kEps = 1e-6f;
constexpr int kNB = 8;                       // z buckets per tile
constexpr int kChunks = 8;                   // face chunks (binning blocks)
constexpr int kFPC = kNF / kChunks;          // 1247 faces per chunk
constexpr int kSplit = 2;                    // raster blocks per tile
constexpr unsigned kListCap = 1800000u;      // u16 entries

// ---------------------------------------------------------------- utilities
__device__ inline void cross3(float ax, float ay, float az,
                              float bx, float by, float bz,
                              float& cx, float& cy, float& cz) {
  cx = ay * bz - az * by;
  cy = az * bx - ax * bz;
  cz = ax * by - ay * bx;
}

// Edge-separation triangle-vs-tile cull. Bit-identical between count and fill
// passes (same fn, same inputs -> deterministic counts).
__device__ inline bool tileCull(const float4 r0, const float4 r1,
                                float tX0, float tX1, float tY0, float tY1) {
  float hi0 = fmaf(r0.x, r0.x >= 0.f ? tX1 : tX0,
                   fmaf(r0.y, r0.y >= 0.f ? tY1 : tY0, r0.z));
  float lo0 = fmaf(r0.x, r0.x >= 0.f ? tX0 : tX1,
                   fmaf(r0.y, r0.y >= 0.f ? tY0 : tY1, r0.z));
  float hi1 = fmaf(r1.x, r1.x >= 0.f ? tX1 : tX0,
                   fmaf(r1.y, r1.y >= 0.f ? tY1 : tY0, r1.z));
  float lo1 = fmaf(r1.x, r1.x >= 0.f ? tX0 : tX1,
                   fmaf(r1.y, r1.y >= 0.f ? tY0 : tY1, r1.z));
  float m2 = 2.f * r0.w;   // looser than the per-pixel margin -mw: conservative
  return hi0 >= -m2 && hi1 >= -m2 && (1.f - lo0 - lo1) >= -m2;
}

__device__ inline int bucketOf(float zminf, float zlo, float iscale) {
  float t = (zminf - zlo) * iscale;
  t = fminf(fmaxf(t, 0.f), (float)(kNB - 1));
  return (int)t;
}

// Exact reference projection (feeds discrete decisions -> _rn, no FMA).
__device__ inline void projectV(const float* __restrict__ vb, int vi,
                                float& px, float& py, float& zc) {
  float vx = vb[3 * vi], vy = vb[3 * vi + 1], vz = vb[3 * vi + 2];
  float xc = -vx, yc = vy;
  zc = -vz;
  float zs = fmaxf(zc, kEps);
  px = __fsub_rn(0.5f * kW, __fdiv_rn(__fmul_rn(kFocal, xc), zs));
  py = __fsub_rn(0.5f * kH, __fdiv_rn(__fmul_rn(kFocal, yc), zs));
}

// ---------------------------------------------------------------- kernels
// FUSED per-(b,f): normal scatter-accumulation (nacc pre-zeroed by memset)
// + face setup with inline exact _rn projection. zr: [0..1]=min (0xFF init),
// [2..3]=max (0 init), [4]=list cursor (0 init).
__global__ void setup_k(const float* __restrict__ verts,
                        const int* __restrict__ faces,
                        float* __restrict__ nacc,
                        float4* __restrict__ fdE,
                        float4* __restrict__ fdP,
                        unsigned* __restrict__ tb,
                        unsigned* __restrict__ zr) {
  int f = blockIdx.x * 256 + threadIdx.x;
  int b = blockIdx.y;
  bool act = (f < kNF);
  float redMin = INFINITY, redMax = 0.0f;   // neutral for inactive/invalid
  if (act) {
    size_t idx = (size_t)b * kNF + f;
    const float* vb = verts + (size_t)b * kNV * 3;
    int i0 = faces[3 * f + 0], i1 = faces[3 * f + 1], i2 = faces[3 * f + 2];
    // ---- normal scatter (raw world-space verts) ----
    {
      float x0 = vb[3 * i0], y0 = vb[3 * i0 + 1], z0 = vb[3 * i0 + 2];
      float x1 = vb[3 * i1], y1 = vb[3 * i1 + 1], z1 = vb[3 * i1 + 2];
      float x2 = vb[3 * i2], y2 = vb[3 * i2 + 1], z2 = vb[3 * i2 + 2];
      float* nb = nacc + (size_t)b * kNV * 3;
      float cx, cy, cz;
      cross3(x2 - x1, y2 - y1, z2 - z1, x0 - x1, y0 - y1, z0 - z1, cx, cy, cz);
      atomicAdd(nb + 3 * i1 + 0, cx);
      atomicAdd(nb + 3 * i1 + 1, cy);
      atomicAdd(nb + 3 * i1 + 2, cz);
      cross3(x0 - x2, y0 - y2, z0 - z2, x1 - x2, y1 - y2, z1 - z2, cx, cy, cz);
      atomicAdd(nb + 3 * i2 + 0, cx);
      atomicAdd(nb + 3 * i2 + 1, cy);
      atomicAdd(nb + 3 * i2 + 2, cz);
      cross3(x1 - x0, y1 - y0, z1 - z0, x2 - x0, y2 - y0, z2 - z0, cx, cy, cz);
      atomicAdd(nb + 3 * i0 + 0, cx);
      atomicAdd(nb + 3 * i0 + 1, cy);
      atomicAdd(nb + 3 * i0 + 2, cz);
    }
    // ---- face setup ----
    float ax, ay, za, bx, by, zb, cx, cy, zc;
    projectV(vb, i0, ax, ay, za);
    projectV(vb, i1, bx, by, zb);
    projectV(vb, i2, cx, cy, zc);
    float A0 = __fsub_rn(by, cy);
    float B0 = __fsub_rn(cx, bx);
    float A1 = __fsub_rn(cy, ay);
    float B1 = __fsub_rn(ax, cx);
    float e = __fsub_rn(ay, cy);
    float den = __fadd_rn(__fmul_rn(A0, B1), __fmul_rn(B0, e));
    bool valid =
        (fabsf(den) >= kEps) && (za > kEps) && (zb > kEps) && (zc > kEps);
    float ds = valid ? den : 1.0f;

    float4* oe = fdE + idx * 3;
    oe[0] = make_float4(cx, cy, A0, B0);
    oe[1] = make_float4(A1, B1, ds, za);
    oe[2] = make_float4(zb, zc, 0.0f, 0.0f);

    float P0 = A0 / ds, Q0 = B0 / ds, R0 = -(A0 * cx + B0 * cy) / ds;
    float P1 = A1 / ds, Q1 = B1 / ds, R1 = -(A1 * cx + B1 * cy) / ds;
    float dza = za - zc, dzb = zb - zc;
    float Zx = dza * P0 + dzb * P1;
    float Zy = dza * Q0 + dzb * Q1;
    float Zc = dza * R0 + dzb * R1 + zc;
    float S0 = (fabsf(P0) + fabsf(Q0)) * 512.f + fabsf(R0);
    float S1 = (fabsf(P1) + fabsf(Q1)) * 512.f + fabsf(R1);
    float Sz = (fabsf(Zx) + fabsf(Zy)) * 512.f + fabsf(Zc);
    float m0 = S0 * 0x1p-18f;
    float m1 = S1 * 0x1p-18f;
    float mw = m0 + m1 + 2e-6f;
    float mz = m0 * fabsf(dza) + m1 * fabsf(dzb) + Sz * 0x1p-18f +
               0x1p-18f * (fabsf(zc) + fabsf(dza) + fabsf(dzb) + 1.f) + 2e-6f;
    float zminf = fminf(fminf(za, zb), zc);

    float4* op = fdP + idx * 3;
    op[0] = make_float4(P0, Q0, R0, mw);
    op[1] = make_float4(P1, Q1, R1, mz);
    op[2] = make_float4(Zx, Zy, Zc, zminf);

    unsigned pack;
    if (valid) {
      float mnx = fminf(fminf(ax, bx), cx) - 0.5f;
      float mxx = fmaxf(fmaxf(ax, bx), cx) + 0.5f;
      float mny = fminf(fminf(ay, by), cy) - 0.5f;
      float mxy = fmaxf(fmaxf(ay, by), cy) + 0.5f;
      float c0 = fminf(fmaxf(ceilf((mnx - 15.5f) * 0.0625f), 0.f), 31.f);
      float c1 = fminf(fmaxf(floorf((mxx - 0.5f) * 0.0625f), 0.f), 31.f);
      float r0 = fminf(fmaxf(ceilf((mny - 15.5f) * 0.0625f), 0.f), 31.f);
      float r1 = fminf(fmaxf(floorf((mxy - 0.5f) * 0.0625f), 0.f), 31.f);
      unsigned uc0 = (unsigned)c0, uc1 = (unsigned)c1;
      unsigned ur0 = (unsigned)r0, ur1 = (unsigned)r1;
      if (mxx < mnx || mxy < mny) { uc0 = 1; uc1 = 0; }   // degenerate guard
      pack = uc0 | (uc1 << 8) | (ur0 << 16) | (ur1 << 24);
      redMin = zminf;   // zminf > eps > 0 -> uint bit-order == float order
      redMax = zminf;
    } else {
      pack = 1u;   // cxlo=1 > cxhi=0 -> empty
    }
    tb[idx] = pack;
  }
  // Wave-level z-range butterfly -> one atomic per wave (R3 lesson).
#pragma unroll
  for (int d = 32; d >= 1; d >>= 1) {
    redMin = fminf(redMin, __shfl_xor(redMin, d, 64));
    redMax = fmaxf(redMax, __shfl_xor(redMax, d, 64));
  }
  if ((threadIdx.x & 63) == 0 && redMin < INFINITY) {
    atomicMin(zr + b, __float_as_uint(redMin));        // zrMin
    atomicMax(zr + 2 + b, __float_as_uint(redMax));    // zrMax
  }
}

// SINGLE-DISPATCH binning (R13 win): LDS count -> intra-block scan -> ONE
// global cursor atomicAdd claims a contiguous segment -> absolute offsets to
// cnt[block][257] -> identical-cull fill. Segment order racy; per-cell SETS
// deterministic; (z,idx) lex-min order-independent -> deterministic output.
__global__ __launch_bounds__(256) void bin_k(
    const float4* __restrict__ fdP, const unsigned* __restrict__ tb,
    unsigned* __restrict__ zr, unsigned* __restrict__ cnt,
    unsigned short* __restrict__ list) {
  __shared__ unsigned lc[256];
  __shared__ unsigned segBase;
  int c = blockIdx.x, ty = blockIdx.y, b = blockIdx.z;
  size_t bOff = (size_t)b * kNF;
  int t = threadIdx.x;
  lc[t] = 0u;
  __syncthreads();

  float tY0 = 16.f * ty + 0.5f, tY1 = tY0 + 15.f;
  float zlo = __uint_as_float(zr[b]);
  float zhi = __uint_as_float(zr[2 + b]);
  float range = zhi - zlo;
  float iscale = range > 1e-30f ? (float)kNB / range : 0.f;
  int f0 = c * kFPC, f1 = min(kNF, f0 + kFPC);

  for (int f = f0 + t; f < f1; f += 256) {
    unsigned pk = tb[bOff + f];
    int cx0 = pk & 0xFF, cx1 = (pk >> 8) & 0xFF;
    int ry0 = (pk >> 16) & 0xFF, ry1 = (pk >> 24) & 0xFF;
    if (ty < ry0 || ty > ry1 || cx0 > cx1) continue;
    const float4* rp = fdP + (bOff + f) * 3;
    float4 r0 = rp[0], r1 = rp[1], r2 = rp[2];
    int q = bucketOf(r2.w, zlo, iscale);
    for (int tx = cx0; tx <= cx1; ++tx) {
      float tX0 = 16.f * tx + 0.5f, tX1 = tX0 + 15.f;
      if (tileCull(r0, r1, tX0, tX1, tY0, tY1))
        atomicAdd(&lc[tx * kNB + q], 1u);
    }
  }
  __syncthreads();

  unsigned own = lc[t];
  for (int d = 1; d < 256; d <<= 1) {
    unsigned w = (t >= d) ? lc[t - d] : 0u;
    __syncthreads();
    lc[t] += w;
    __syncthreads();
  }
  unsigned excl = lc[t] - own;
  unsigned tot = lc[255];
  if (t == 0) segBase = atomicAdd(&zr[4], tot);
  __syncthreads();
  unsigned sb = segBase;

  unsigned blk = ((unsigned)(b * 32 + ty) * kChunks + (unsigned)c);
  cnt[blk * 257 + t] = sb + excl;
  if (t == 0) cnt[blk * 257 + 256] = sb + tot;
  __syncthreads();
  lc[t] = sb + excl;
  __syncthreads();

  for (int f = f0 + t; f < f1; f += 256) {
    unsigned pk = tb[bOff + f];
    int cx0 = pk & 0xFF, cx1 = (pk >> 8) & 0xFF;
    int ry0 = (pk >> 16) & 0xFF, ry1 = (pk >> 24) & 0xFF;
    if (ty < ry0 || ty > ry1 || cx0 > cx1) continue;
    const float4* rp = fdP + (bOff + f) * 3;
    float4 r0 = rp[0], r1 = rp[1], r2 = rp[2];
    int q = bucketOf(r2.w, zlo, iscale);
    for (int tx = cx0; tx <= cx1; ++tx) {
      float tX0 = 16.f * tx + 0.5f, tX1 = tX0 + 15.f;
      if (tileCull(r0, r1, tX0, tX1, tY0, tY1)) {
        unsigned pos = atomicAdd(&lc[tx * kNB + q], 1u);
        if (pos < kListCap) list[pos] = (unsigned short)f;
      }
    }
  }
}

// Tile raster, SPLIT x2 across blocks; grid.z = b*2+s; split s takes strided
// candidates idx = s + 2j of each bucket's concatenated list. R14 lesson
// (R4 redux): the u64 atomicMin merge was a scattered-atomic write storm
// (WRITE_SIZE 7.8->13MB, raster 83->126us). Fix: PLAIN SLOT STORES --
// d_out is 16B/px = two u64 slots; split s writes its partial key (or ~0
// sentinel) to slot s unconditionally. No atomics, no init memset (both
// slots always written for every real pixel). shade_k takes min of the two
// = global (z,idx) lex-min == jnp.argmin first-min -> deterministic.
__global__ __launch_bounds__(256) void raster_k(
    const float4* __restrict__ fdP, const float4* __restrict__ fdE,
    const unsigned* __restrict__ cnt, const unsigned short* __restrict__ list,
    const unsigned* __restrict__ zr, unsigned long long* __restrict__ keys) {
  __shared__ float4 sA[256], sB[256], sC[256];   // 12 KiB stage
  __shared__ unsigned sOff[kChunks * 9];
  int bz = blockIdx.z;
  int b = bz >> 1, s = bz & 1;
  size_t bOff = (size_t)b * kNF;
  int t = threadIdx.x;
  int tx = t & 15, ty = t >> 4;
  int x = blockIdx.x * 16 + tx;
  int y = blockIdx.y * 16 + ty;
  float xp = (float)x + 0.5f;
  float yp = (float)y + 0.5f;
  bool live = (x < kW && y < kH);
  float zmin = live ? INFINITY : -INFINITY;   // dead px never block the break
  int best = 0x7FFFFFFF;

  float zlo = __uint_as_float(zr[b]);
  float zhi = __uint_as_float(zr[2 + b]);
  float range = zhi - zlo;
  float bwid = range > 1e-30f ? range * (1.f / kNB) : 0.f;

  if (t < kChunks * 9) {
    int c = t / 9, j = t - c * 9;
    unsigned blk = ((unsigned)(b * 32 + blockIdx.y) * kChunks + (unsigned)c);
    sOff[t] = cnt[blk * 257 + blockIdx.x * 8 + j];
  }
  __syncthreads();

  for (int q = 0; q < kNB; ++q) {
    if (q > 0) {
      float lb = zlo + (float)q * bwid * (1.f - 1e-5f) - 2e-5f;
      if (__syncthreads_and(zmin < lb)) break;
    }
    unsigned st[kChunks], pre[kChunks + 1];
    pre[0] = 0;
#pragma unroll
    for (int c = 0; c < kChunks; ++c) {
      unsigned s0 = sOff[c * 9 + q], e0 = sOff[c * 9 + q + 1];
      st[c] = s0;
      pre[c + 1] = pre[c] + (e0 - s0);
    }
    unsigned m = pre[kChunks];
    unsigned mS = (m > (unsigned)s) ? (m - s + 1) >> 1 : 0u;   // strided count
    for (unsigned base = 0; base < mS; base += 256) {
      int n = min(256u, mS - base);
      __syncthreads();
      if (t < n) {
        unsigned idx = (base + t) * 2 + s, src = 0;
#pragma unroll
        for (int c = 0; c < kChunks; ++c)
          if (idx >= pre[c] && idx < pre[c + 1]) src = st[c] + (idx - pre[c]);
        unsigned fi = list[src];
        const float4* rp = fdP + (bOff + fi) * 3;
        float4 r0 = rp[0], r1 = rp[1], r2 = rp[2];
        r2.w = __int_as_float((int)fi);
        sA[t] = r0;
        sB[t] = r1;
        sC[t] = r2;
      }
      __syncthreads();
      for (int k = 0; k < n; ++k) {
        float4 a = sA[k], bq = sB[k], c = sC[k];
        float w0a = fmaf(a.x, xp, fmaf(a.y, yp, a.z));
        float w1a = fmaf(bq.x, xp, fmaf(bq.y, yp, bq.z));
        float w2a = 1.f - w0a - w1a;
        float zl = fmaf(c.x, xp, fmaf(c.y, yp, c.z));
        float wmin = fminf(fminf(w0a, w1a), w2a);
        if (wmin >= -a.w && zl <= zmin + bq.w) {
          // Exact path: replicate reference fp32 rounding bit-for-bit.
          int fi = __float_as_int(c.w);
          const float4* ep = fdE + (bOff + fi) * 3;
          float4 e0 = ep[0], e1 = ep[1], e2 = ep[2];
          float dx = __fsub_rn(xp, e0.x), dy = __fsub_rn(yp, e0.y);
          float num0 = __fadd_rn(__fmul_rn(e0.z, dx), __fmul_rn(e0.w, dy));
          float num1 = __fadd_rn(__fmul_rn(e1.x, dx), __fmul_rn(e1.y, dy));
          float w0 = __fdiv_rn(num0, e1.z);
          float w1 = __fdiv_rn(num1, e1.z);
          float w2 = __fsub_rn(__fsub_rn(1.f, w0), w1);
          if (w0 >= 0.f && w1 >= 0.f && w2 >= 0.f) {
            float z = __fadd_rn(
                __fadd_rn(__fmul_rn(w0, e1.w), __fmul_rn(w1, e2.x)),
                __fmul_rn(w2, e2.y));
            if (z < zmin || (z == zmin && fi < best)) { zmin = z; best = fi; }
          }
        }
      }
    }
  }

  if (live) {
    unsigned long long key =
        (zmin < INFINITY)
            ? (((unsigned long long)__float_as_uint(zmin) << 32) |
               (unsigned)best)
            : ~0ull;
    keys[(((size_t)b * kH + y) * kW + x) * 2 + s] = key;   // plain store
  }
}

// Per pixel: merge the two split keys (min = lex-min), recompute exact
// barycentrics (bit-identical to raster's exact path), shade, overwrite.
__global__ void shade_k(const float4* __restrict__ fdE,
                        const float* __restrict__ verts,
                        const float* __restrict__ nacc,
                        const int* __restrict__ faces,
                        float* __restrict__ out) {
  int p = blockIdx.x * 256 + threadIdx.x;
  if (p >= kB * kH * kW) return;
  int b = p / (kH * kW);
  int r = p - b * kH * kW;
  int y = r / kW, x = r - y * kW;
  unsigned long long k0 = ((const unsigned long long*)out)[(size_t)p * 2];
  unsigned long long k1 = ((const unsigned long long*)out)[(size_t)p * 2 + 1];
  unsigned long long key = min(k0, k1);
  float rv, av;
  if (key == ~0ull) {
    rv = 1.0f; av = 0.0f;
  } else {
    int fi = (int)(key & 0xFFFFFFFFull);
    float xp = (float)x + 0.5f, yp = (float)y + 0.5f;
    const float4* ep = fdE + ((size_t)b * kNF + fi) * 3;
    float4 e0 = ep[0], e1 = ep[1];
    float dx = __fsub_rn(xp, e0.x), dy = __fsub_rn(yp, e0.y);
    float num0 = __fadd_rn(__fmul_rn(e0.z, dx), __fmul_rn(e0.w, dy));
    float num1 = __fadd_rn(__fmul_rn(e1.x, dx), __fmul_rn(e1.y, dy));
    float w0 = __fdiv_rn(num0, e1.z);
    float w1 = __fdiv_rn(num1, e1.z);
    float w2 = __fsub_rn(__fsub_rn(1.f, w0), w1);
    int i0 = faces[3 * fi + 0], i1 = faces[3 * fi + 1], i2 = faces[3 * fi + 2];
    const float* vb = verts + (size_t)b * kNV * 3;
    const float* nb = nacc + (size_t)b * kNV * 3;
    float n0x = nb[3 * i0], n0y = nb[3 * i0 + 1], n0z = nb[3 * i0 + 2];
    float n1x = nb[3 * i1], n1y = nb[3 * i1 + 1], n1z = nb[3 * i1 + 2];
    float n2x = nb[3 * i2], n2y = nb[3 * i2 + 1], n2z = nb[3 * i2 + 2];
    float d0 = fmaxf(sqrtf(n0x * n0x + n0y * n0y + n0z * n0z), kEps);
    float d1 = fmaxf(sqrtf(n1x * n1x + n1y * n1y + n1z * n1z), kEps);
    float d2 = fmaxf(sqrtf(n2x * n2x + n2y * n2y + n2z * n2z), kEps);
    n0x /= d0; n0y /= d0; n0z /= d0;
    n1x /= d1; n1y /= d1; n1z /= d1;
    n2x /= d2; n2y /= d2; n2z /= d2;
    float px_ = w0 * vb[3 * i0 + 0] + w1 * vb[3 * i1 + 0] + w2 * vb[3 * i2 + 0];
    float py_ = w0 * vb[3 * i0 + 1] + w1 * vb[3 * i1 + 1] + w2 * vb[3 * i2 + 1];
    float pz_ = w0 * vb[3 * i0 + 2] + w1 * vb[3 * i1 + 2] + w2 * vb[3 * i2 + 2];
    float nx = w0 * n0x + w1 * n1x + w2 * n2x;
    float ny = w0 * n0y + w1 * n1y + w2 * n2y;
    float nz = w0 * n0z + w1 * n1z + w2 * n2z;
    float nn = sqrtf(nx * nx + ny * ny + nz * nz);
    float nd = fmaxf(nn, kEps);
    nx /= nd; ny /= nd; nz /= nd;
    float pn = sqrtf(px_ * px_ + py_ * py_ + pz_ * pz_);
    float pd = fmaxf(pn, kEps);
    float lx = -px_ / pd, ly = -py_ / pd, lz = -pz_ / pd;
    float sdot = nx * lx + ny * ly + nz * lz;
    float ndl = fmaxf(sdot, 0.0f);
    float rx = 2.0f * sdot * nx - lx;
    float ry = 2.0f * sdot * ny - ly;
    float rz = 2.0f * sdot * nz - lz;
    float vdr = fmaxf(lx * rx + ly * ry + lz * rz, 0.0f);
    float qv = vdr;   // vdr^64 via 6 squarings
    qv = qv * qv; qv = qv * qv; qv = qv * qv;
    qv = qv * qv; qv = qv * qv; qv = qv * qv;
    float shade = 0.5f * (0.5f + 0.3f * ndl) + 0.2f * qv;
    rv = fminf(fmaxf(shade, 0.0f), 255.0f);
    av = 1.0f;
  }
  ((float4*)out)[p] = make_float4(rv, rv, rv, av);
}

}  // namespace

extern "C" void kernel_launch(void* const* d_in, const int* in_sizes, int n_in,
                              void* d_out, int out_size, void* d_ws, size_t ws_size,
                              hipStream_t stream) {
  (void)in_sizes; (void)n_in; (void)out_size; (void)ws_size;
  const float* verts = (const float*)d_in[0];   // (B, NV, 3) f32
  const int* faces = (const int*)d_in[1];       // (NF, 3) i32
  float* out = (float*)d_out;                   // (B, H, W, 4) f32
  float* ws = (float*)d_ws;

  // ws layout (float offsets; total ~6.41 MB <= proven ws >= 6.52 MB):
  //   nacc @ 0          (30,138)
  //   fdE  @ 71,680     (float4 x 59,856)
  //   fdP  @ 311,296    (float4 x 59,856)
  //   tb   @ 550,912    (u32 x 19,952)
  //   zr   @ 570,880    (u32 x 8: [0..1]=min(0xFF) [2..3]=max(0) [4]=cursor(0))
  //   cnt  @ 571,008    (u32 x 512*257)
  //   list @ 702,720    (u16 x 1,800,000)
  float* nacc = ws;
  float4* fdE = (float4*)(ws + 71680);
  float4* fdP = (float4*)(ws + 311296);
  unsigned* tb = (unsigned*)(ws + 550912);
  unsigned* zr = (unsigned*)(ws + 570880);
  unsigned* cnt = (unsigned*)(ws + 571008);
  unsigned short* list = (unsigned short*)(ws + 702720);

  hipMemsetAsync(nacc, 0, (size_t)kB * kNV * 3 * sizeof(float), stream);
  hipMemsetAsync(zr, 0xFF, 2 * sizeof(unsigned), stream);       // zrMin
  hipMemsetAsync(zr + 2, 0x00, 3 * sizeof(unsigned), stream);   // zrMax+cursor

  hipLaunchKernelGGL(setup_k, dim3((kNF + 255) / 256, kB), dim3(256), 0,
                     stream, verts, faces, nacc, fdE, fdP, tb, zr);
  hipLaunchKernelGGL(bin_k, dim3(kChunks, 32, kB), dim3(256), 0,
                     stream, fdP, tb, zr, cnt, list);
  hipLaunchKernelGGL(raster_k, dim3(32, 32, kB * kSplit), dim3(256), 0, stream,
                     fdP, fdE, cnt, list, zr, (unsigned long long*)out);
  hipLaunchKernelGGL(shade_k, dim3((kB * kH * kW + 255) / 256), dim3(256), 0,
                     stream, fdE, verts, nacc, faces, out);
}

// Round 17
// 148.115 us; speedup vs baseline: 1.3036x; 1.2886x over previous
//
#include <hip/hip_runtime.h>
#include <math.h>

namespace {

constexpr int kH = 500, kW = 500, kNV = 5023, kNF = 9976, kB = 2;
constexpr float kFocal = 1015.0f;
constexpr float kEps = 1e-6f;
constexpr int kNB = 8;                       // z buckets per tile
constexpr int kChunks = 8;                   // face chunks (binning blocks)
constexpr int kFPC = kNF / kChunks;          // 1247 faces per chunk
constexpr unsigned kListCap = 1800000u;      // u16 entries

// ---------------------------------------------------------------- utilities
__device__ inline void cross3(float ax, float ay, float az,
                              float bx, float by, float bz,
                              float& cx, float& cy, float& cz) {
  cx = ay * bz - az * by;
  cy = az * bx - ax * bz;
  cz = ax * by - ay * bx;
}

// Edge-separation triangle-vs-tile cull. Bit-identical between count and fill
// passes (same fn, same inputs -> deterministic counts).
__device__ inline bool tileCull(const float4 r0, const float4 r1,
                                float tX0, float tX1, float tY0, float tY1) {
  float hi0 = fmaf(r0.x, r0.x >= 0.f ? tX1 : tX0,
                   fmaf(r0.y, r0.y >= 0.f ? tY1 : tY0, r0.z));
  float lo0 = fmaf(r0.x, r0.x >= 0.f ? tX0 : tX1,
                   fmaf(r0.y, r0.y >= 0.f ? tY0 : tY1, r0.z));
  float hi1 = fmaf(r1.x, r1.x >= 0.f ? tX1 : tX0,
                   fmaf(r1.y, r1.y >= 0.f ? tY1 : tY0, r1.z));
  float lo1 = fmaf(r1.x, r1.x >= 0.f ? tX0 : tX1,
                   fmaf(r1.y, r1.y >= 0.f ? tY0 : tY1, r1.z));
  float m2 = 2.f * r0.w;   // looser than the per-pixel margin -mw: conservative
  return hi0 >= -m2 && hi1 >= -m2 && (1.f - lo0 - lo1) >= -m2;
}

__device__ inline int bucketOf(float zminf, float zlo, float iscale) {
  float t = (zminf - zlo) * iscale;
  t = fminf(fmaxf(t, 0.f), (float)(kNB - 1));
  return (int)t;
}

// Exact reference projection (feeds discrete decisions -> _rn, no FMA).
__device__ inline void projectV(const float* __restrict__ vb, int vi,
                                float& px, float& py, float& zc) {
  float vx = vb[3 * vi], vy = vb[3 * vi + 1], vz = vb[3 * vi + 2];
  float xc = -vx, yc = vy;
  zc = -vz;
  float zs = fmaxf(zc, kEps);
  px = __fsub_rn(0.5f * kW, __fdiv_rn(__fmul_rn(kFocal, xc), zs));
  py = __fsub_rn(0.5f * kH, __fdiv_rn(__fmul_rn(kFocal, yc), zs));
}

// ---------------------------------------------------------------- kernels
// FUSED per-(b,f): normal scatter-accumulation (nacc pre-zeroed by memset)
// + face setup with inline exact _rn projection. zr: [0..1]=min (0xFF init),
// [2..3]=max (0 init), [4]=list cursor (0 init).
__global__ void setup_k(const float* __restrict__ verts,
                        const int* __restrict__ faces,
                        float* __restrict__ nacc,
                        float4* __restrict__ fdE,
                        float4* __restrict__ fdP,
                        unsigned* __restrict__ tb,
                        unsigned* __restrict__ zr) {
  int f = blockIdx.x * 256 + threadIdx.x;
  int b = blockIdx.y;
  bool act = (f < kNF);
  float redMin = INFINITY, redMax = 0.0f;   // neutral for inactive/invalid
  if (act) {
    size_t idx = (size_t)b * kNF + f;
    const float* vb = verts + (size_t)b * kNV * 3;
    int i0 = faces[3 * f + 0], i1 = faces[3 * f + 1], i2 = faces[3 * f + 2];
    // ---- normal scatter (raw world-space verts) ----
    {
      float x0 = vb[3 * i0], y0 = vb[3 * i0 + 1], z0 = vb[3 * i0 + 2];
      float x1 = vb[3 * i1], y1 = vb[3 * i1 + 1], z1 = vb[3 * i1 + 2];
      float x2 = vb[3 * i2], y2 = vb[3 * i2 + 1], z2 = vb[3 * i2 + 2];
      float* nb = nacc + (size_t)b * kNV * 3;
      float cx, cy, cz;
      cross3(x2 - x1, y2 - y1, z2 - z1, x0 - x1, y0 - y1, z0 - z1, cx, cy, cz);
      atomicAdd(nb + 3 * i1 + 0, cx);
      atomicAdd(nb + 3 * i1 + 1, cy);
      atomicAdd(nb + 3 * i1 + 2, cz);
      cross3(x0 - x2, y0 - y2, z0 - z2, x1 - x2, y1 - y2, z1 - z2, cx, cy, cz);
      atomicAdd(nb + 3 * i2 + 0, cx);
      atomicAdd(nb + 3 * i2 + 1, cy);
      atomicAdd(nb + 3 * i2 + 2, cz);
      cross3(x1 - x0, y1 - y0, z1 - z0, x2 - x0, y2 - y0, z2 - z0, cx, cy, cz);
      atomicAdd(nb + 3 * i0 + 0, cx);
      atomicAdd(nb + 3 * i0 + 1, cy);
      atomicAdd(nb + 3 * i0 + 2, cz);
    }
    // ---- face setup ----
    float ax, ay, za, bx, by, zb, cx, cy, zc;
    projectV(vb, i0, ax, ay, za);
    projectV(vb, i1, bx, by, zb);
    projectV(vb, i2, cx, cy, zc);
    float A0 = __fsub_rn(by, cy);
    float B0 = __fsub_rn(cx, bx);
    float A1 = __fsub_rn(cy, ay);
    float B1 = __fsub_rn(ax, cx);
    float e = __fsub_rn(ay, cy);
    float den = __fadd_rn(__fmul_rn(A0, B1), __fmul_rn(B0, e));
    bool valid =
        (fabsf(den) >= kEps) && (za > kEps) && (zb > kEps) && (zc > kEps);
    float ds = valid ? den : 1.0f;

    float4* oe = fdE + idx * 3;
    oe[0] = make_float4(cx, cy, A0, B0);
    oe[1] = make_float4(A1, B1, ds, za);
    oe[2] = make_float4(zb, zc, 0.0f, 0.0f);

    float P0 = A0 / ds, Q0 = B0 / ds, R0 = -(A0 * cx + B0 * cy) / ds;
    float P1 = A1 / ds, Q1 = B1 / ds, R1 = -(A1 * cx + B1 * cy) / ds;
    float dza = za - zc, dzb = zb - zc;
    float Zx = dza * P0 + dzb * P1;
    float Zy = dza * Q0 + dzb * Q1;
    float Zc = dza * R0 + dzb * R1 + zc;
    float S0 = (fabsf(P0) + fabsf(Q0)) * 512.f + fabsf(R0);
    float S1 = (fabsf(P1) + fabsf(Q1)) * 512.f + fabsf(R1);
    float Sz = (fabsf(Zx) + fabsf(Zy)) * 512.f + fabsf(Zc);
    float m0 = S0 * 0x1p-18f;
    float m1 = S1 * 0x1p-18f;
    float mw = m0 + m1 + 2e-6f;
    float mz = m0 * fabsf(dza) + m1 * fabsf(dzb) + Sz * 0x1p-18f +
               0x1p-18f * (fabsf(zc) + fabsf(dza) + fabsf(dzb) + 1.f) + 2e-6f;
    float zminf = fminf(fminf(za, zb), zc);

    float4* op = fdP + idx * 3;
    op[0] = make_float4(P0, Q0, R0, mw);
    op[1] = make_float4(P1, Q1, R1, mz);
    op[2] = make_float4(Zx, Zy, Zc, zminf);

    unsigned pack;
    if (valid) {
      float mnx = fminf(fminf(ax, bx), cx) - 0.5f;
      float mxx = fmaxf(fmaxf(ax, bx), cx) + 0.5f;
      float mny = fminf(fminf(ay, by), cy) - 0.5f;
      float mxy = fmaxf(fmaxf(ay, by), cy) + 0.5f;
      float c0 = fminf(fmaxf(ceilf((mnx - 15.5f) * 0.0625f), 0.f), 31.f);
      float c1 = fminf(fmaxf(floorf((mxx - 0.5f) * 0.0625f), 0.f), 31.f);
      float r0 = fminf(fmaxf(ceilf((mny - 15.5f) * 0.0625f), 0.f), 31.f);
      float r1 = fminf(fmaxf(floorf((mxy - 0.5f) * 0.0625f), 0.f), 31.f);
      unsigned uc0 = (unsigned)c0, uc1 = (unsigned)c1;
      unsigned ur0 = (unsigned)r0, ur1 = (unsigned)r1;
      if (mxx < mnx || mxy < mny) { uc0 = 1; uc1 = 0; }   // degenerate guard
      pack = uc0 | (uc1 << 8) | (ur0 << 16) | (ur1 << 24);
      redMin = zminf;   // zminf > eps > 0 -> uint bit-order == float order
      redMax = zminf;
    } else {
      pack = 1u;   // cxlo=1 > cxhi=0 -> empty
    }
    tb[idx] = pack;
  }
  // Wave-level z-range butterfly -> one atomic per wave (R3 lesson).
#pragma unroll
  for (int d = 32; d >= 1; d >>= 1) {
    redMin = fminf(redMin, __shfl_xor(redMin, d, 64));
    redMax = fmaxf(redMax, __shfl_xor(redMax, d, 64));
  }
  if ((threadIdx.x & 63) == 0 && redMin < INFINITY) {
    atomicMin(zr + b, __float_as_uint(redMin));        // zrMin
    atomicMax(zr + 2 + b, __float_as_uint(redMax));    // zrMax
  }
}

// SINGLE-DISPATCH binning (R13 win): LDS count -> intra-block scan -> ONE
// global cursor atomicAdd claims a contiguous segment -> absolute offsets to
// cnt[block][257] -> identical-cull fill. Segment order racy; per-cell SETS
// deterministic; (z,idx) lex-min order-independent -> deterministic output.
__global__ __launch_bounds__(256) void bin_k(
    const float4* __restrict__ fdP, const unsigned* __restrict__ tb,
    unsigned* __restrict__ zr, unsigned* __restrict__ cnt,
    unsigned short* __restrict__ list) {
  __shared__ unsigned lc[256];
  __shared__ unsigned segBase;
  int c = blockIdx.x, ty = blockIdx.y, b = blockIdx.z;
  size_t bOff = (size_t)b * kNF;
  int t = threadIdx.x;
  lc[t] = 0u;
  __syncthreads();

  float tY0 = 16.f * ty + 0.5f, tY1 = tY0 + 15.f;
  float zlo = __uint_as_float(zr[b]);
  float zhi = __uint_as_float(zr[2 + b]);
  float range = zhi - zlo;
  float iscale = range > 1e-30f ? (float)kNB / range : 0.f;
  int f0 = c * kFPC, f1 = min(kNF, f0 + kFPC);

  for (int f = f0 + t; f < f1; f += 256) {
    unsigned pk = tb[bOff + f];
    int cx0 = pk & 0xFF, cx1 = (pk >> 8) & 0xFF;
    int ry0 = (pk >> 16) & 0xFF, ry1 = (pk >> 24) & 0xFF;
    if (ty < ry0 || ty > ry1 || cx0 > cx1) continue;
    const float4* rp = fdP + (bOff + f) * 3;
    float4 r0 = rp[0], r1 = rp[1], r2 = rp[2];
    int q = bucketOf(r2.w, zlo, iscale);
    for (int tx = cx0; tx <= cx1; ++tx) {
      float tX0 = 16.f * tx + 0.5f, tX1 = tX0 + 15.f;
      if (tileCull(r0, r1, tX0, tX1, tY0, tY1))
        atomicAdd(&lc[tx * kNB + q], 1u);
    }
  }
  __syncthreads();

  unsigned own = lc[t];
  for (int d = 1; d < 256; d <<= 1) {
    unsigned w = (t >= d) ? lc[t - d] : 0u;
    __syncthreads();
    lc[t] += w;
    __syncthreads();
  }
  unsigned excl = lc[t] - own;
  unsigned tot = lc[255];
  if (t == 0) segBase = atomicAdd(&zr[4], tot);
  __syncthreads();
  unsigned sb = segBase;

  unsigned blk = ((unsigned)(b * 32 + ty) * kChunks + (unsigned)c);
  cnt[blk * 257 + t] = sb + excl;
  if (t == 0) cnt[blk * 257 + 256] = sb + tot;
  __syncthreads();
  lc[t] = sb + excl;
  __syncthreads();

  for (int f = f0 + t; f < f1; f += 256) {
    unsigned pk = tb[bOff + f];
    int cx0 = pk & 0xFF, cx1 = (pk >> 8) & 0xFF;
    int ry0 = (pk >> 16) & 0xFF, ry1 = (pk >> 24) & 0xFF;
    if (ty < ry0 || ty > ry1 || cx0 > cx1) continue;
    const float4* rp = fdP + (bOff + f) * 3;
    float4 r0 = rp[0], r1 = rp[1], r2 = rp[2];
    int q = bucketOf(r2.w, zlo, iscale);
    for (int tx = cx0; tx <= cx1; ++tx) {
      float tX0 = 16.f * tx + 0.5f, tX1 = tX0 + 15.f;
      if (tileCull(r0, r1, tX0, tX1, tY0, tY1)) {
        unsigned pos = atomicAdd(&lc[tx * kNB + q], 1u);
        if (pos < kListCap) list[pos] = (unsigned short)f;
      }
    }
  }
}

// 16x16-pixel tile per 256-thread block -- the R13 measured-best structure
// (83us raster; splits/dbuf/flat/coop all worse, R5-R15 ledger). Per z-bucket
// (front-to-back): conservative early-break via __syncthreads_and; per
// 256-candidate chunk: barrier, LDS stage from the concatenation of the 8
// chunk subranges, barrier, compute. NEW vs R13: wave-level compute-skip --
// a wave whose 64 px all beat lb(q) skips the chunk's compute (joins all
// barriers; bound identical to the block-break bound -> strictly safe).
// Discrete decisions replicate reference fp32 rounding; (z,idx) lex-min ==
// jnp.argmin first-min. Shading fused; normals normalized here.
__global__ __launch_bounds__(256) void raster_k(
    const float4* __restrict__ fdP, const float4* __restrict__ fdE,
    const unsigned* __restrict__ cnt, const unsigned short* __restrict__ list,
    const unsigned* __restrict__ zr, const float* __restrict__ verts,
    const float* __restrict__ nacc, const int* __restrict__ faces,
    float* __restrict__ out) {
  __shared__ float4 sA[256], sB[256], sC[256];   // 12 KiB stage
  __shared__ unsigned sOff[kChunks * 9];         // 8 chunks x (8 buckets + end)
  int b = blockIdx.z;
  size_t bOff = (size_t)b * kNF;
  int t = threadIdx.x;
  int tx = t & 15, ty = t >> 4;
  int x = blockIdx.x * 16 + tx;
  int y = blockIdx.y * 16 + ty;
  float xp = (float)x + 0.5f;
  float yp = (float)y + 0.5f;
  bool live = (x < kW && y < kH);
  float zmin = live ? INFINITY : -INFINITY;   // dead px never block the break
  int best = 0x7FFFFFFF;
  float bw0 = 0.f, bw1 = 0.f, bw2 = 0.f;

  float zlo = __uint_as_float(zr[b]);
  float zhi = __uint_as_float(zr[2 + b]);
  float range = zhi - zlo;
  float bwid = range > 1e-30f ? range * (1.f / kNB) : 0.f;

  if (t < kChunks * 9) {
    int c = t / 9, j = t - c * 9;
    unsigned blk = ((unsigned)(b * 32 + blockIdx.y) * kChunks + (unsigned)c);
    sOff[t] = cnt[blk * 257 + blockIdx.x * 8 + j];
  }
  __syncthreads();

  for (int q = 0; q < kNB; ++q) {
    float lbq = zlo + (float)q * bwid * (1.f - 1e-5f) - 2e-5f;
    if (q > 0) {
      if (__syncthreads_and(zmin < lbq)) break;
    }
    // Concatenated subranges for this bucket (registers, static indices).
    unsigned st[kChunks], pre[kChunks + 1];
    pre[0] = 0;
#pragma unroll
    for (int c = 0; c < kChunks; ++c) {
      unsigned s0 = sOff[c * 9 + q], e0 = sOff[c * 9 + q + 1];
      st[c] = s0;
      pre[c + 1] = pre[c] + (e0 - s0);
    }
    unsigned m = pre[kChunks];
    for (unsigned base = 0; base < m; base += 256) {
      int n = min(256u, m - base);
      __syncthreads();
      if (t < n) {
        unsigned idx = base + t, src = 0;
#pragma unroll
        for (int c = 0; c < kChunks; ++c)
          if (idx >= pre[c] && idx < pre[c + 1]) src = st[c] + (idx - pre[c]);
        unsigned fi = list[src];
        const float4* rp = fdP + (bOff + fi) * 3;
        float4 r0 = rp[0], r1 = rp[1], r2 = rp[2];
        r2.w = __int_as_float((int)fi);
        sA[t] = r0;
        sB[t] = r1;
        sC[t] = r2;
      }
      __syncthreads();
      // Wave-level compute skip (q>0 only; bound == block-break bound).
      if (q > 0 && __all(zmin < lbq)) continue;
      for (int k = 0; k < n; ++k) {
        float4 a = sA[k], bq = sB[k], c = sC[k];
        float w0a = fmaf(a.x, xp, fmaf(a.y, yp, a.z));
        float w1a = fmaf(bq.x, xp, fmaf(bq.y, yp, bq.z));
        float w2a = 1.f - w0a - w1a;
        float zl = fmaf(c.x, xp, fmaf(c.y, yp, c.z));
        float wmin = fminf(fminf(w0a, w1a), w2a);
        if (wmin >= -a.w && zl <= zmin + bq.w) {
          // Exact path: replicate reference fp32 rounding bit-for-bit.
          int fi = __float_as_int(c.w);
          const float4* ep = fdE + (bOff + fi) * 3;
          float4 e0 = ep[0], e1 = ep[1], e2 = ep[2];
          float dx = __fsub_rn(xp, e0.x), dy = __fsub_rn(yp, e0.y);
          float num0 = __fadd_rn(__fmul_rn(e0.z, dx), __fmul_rn(e0.w, dy));
          float num1 = __fadd_rn(__fmul_rn(e1.x, dx), __fmul_rn(e1.y, dy));
          float w0 = __fdiv_rn(num0, e1.z);
          float w1 = __fdiv_rn(num1, e1.z);
          float w2 = __fsub_rn(__fsub_rn(1.f, w0), w1);
          if (w0 >= 0.f && w1 >= 0.f && w2 >= 0.f) {
            float z = __fadd_rn(
                __fadd_rn(__fmul_rn(w0, e1.w), __fmul_rn(w1, e2.x)),
                __fmul_rn(w2, e2.y));
            if (z < zmin || (z == zmin && fi < best)) {
              zmin = z; best = fi; bw0 = w0; bw1 = w1; bw2 = w2;
            }
          }
        }
      }
    }
  }

  if (!live) return;

  float rv, av;
  if (zmin < INFINITY) {
    int i0 = faces[3 * best + 0], i1 = faces[3 * best + 1], i2 = faces[3 * best + 2];
    const float* vb = verts + (size_t)b * kNV * 3;
    const float* nb = nacc + (size_t)b * kNV * 3;
    float n0x = nb[3 * i0], n0y = nb[3 * i0 + 1], n0z = nb[3 * i0 + 2];
    float n1x = nb[3 * i1], n1y = nb[3 * i1 + 1], n1z = nb[3 * i1 + 2];
    float n2x = nb[3 * i2], n2y = nb[3 * i2 + 1], n2z = nb[3 * i2 + 2];
    float d0 = fmaxf(sqrtf(n0x * n0x + n0y * n0y + n0z * n0z), kEps);
    float d1 = fmaxf(sqrtf(n1x * n1x + n1y * n1y + n1z * n1z), kEps);
    float d2 = fmaxf(sqrtf(n2x * n2x + n2y * n2y + n2z * n2z), kEps);
    n0x /= d0; n0y /= d0; n0z /= d0;
    n1x /= d1; n1y /= d1; n1z /= d1;
    n2x /= d2; n2y /= d2; n2z /= d2;
    float px_ = bw0 * vb[3 * i0 + 0] + bw1 * vb[3 * i1 + 0] + bw2 * vb[3 * i2 + 0];
    float py_ = bw0 * vb[3 * i0 + 1] + bw1 * vb[3 * i1 + 1] + bw2 * vb[3 * i2 + 1];
    float pz_ = bw0 * vb[3 * i0 + 2] + bw1 * vb[3 * i1 + 2] + bw2 * vb[3 * i2 + 2];
    float nx = bw0 * n0x + bw1 * n1x + bw2 * n2x;
    float ny = bw0 * n0y + bw1 * n1y + bw2 * n2y;
    float nz = bw0 * n0z + bw1 * n1z + bw2 * n2z;
    float nn = sqrtf(nx * nx + ny * ny + nz * nz);
    float nd = fmaxf(nn, kEps);
    nx /= nd; ny /= nd; nz /= nd;
    float pn = sqrtf(px_ * px_ + py_ * py_ + pz_ * pz_);
    float pd = fmaxf(pn, kEps);
    float lx = -px_ / pd, ly = -py_ / pd, lz = -pz_ / pd;
    float sdot = nx * lx + ny * ly + nz * lz;
    float ndl = fmaxf(sdot, 0.0f);
    float rx = 2.0f * sdot * nx - lx;
    float ry = 2.0f * sdot * ny - ly;
    float rz = 2.0f * sdot * nz - lz;
    float vdr = fmaxf(lx * rx + ly * ry + lz * rz, 0.0f);
    float qv = vdr;   // vdr^64 via 6 squarings
    qv = qv * qv; qv = qv * qv; qv = qv * qv;
    qv = qv * qv; qv = qv * qv; qv = qv * qv;
    float shade = 0.5f * (0.5f + 0.3f * ndl) + 0.2f * qv;
    rv = fminf(fmaxf(shade, 0.0f), 255.0f);
    av = 1.0f;
  } else {
    rv = 1.0f;
    av = 0.0f;
  }
  ((float4*)out)[((size_t)b * kH + y) * kW + x] = make_float4(rv, rv, rv, av);
}

}  // namespace

extern "C" void kernel_launch(void* const* d_in, const int* in_sizes, int n_in,
                              void* d_out, int out_size, void* d_ws, size_t ws_size,
                              hipStream_t stream) {
  (void)in_sizes; (void)n_in; (void)out_size; (void)ws_size;
  const float* verts = (const float*)d_in[0];   // (B, NV, 3) f32
  const int* faces = (const int*)d_in[1];       // (NF, 3) i32
  float* out = (float*)d_out;                   // (B, H, W, 4) f32
  float* ws = (float*)d_ws;

  // ws layout (float offsets; total ~6.41 MB <= proven ws >= 6.52 MB):
  //   nacc @ 0          (30,138)
  //   fdE  @ 71,680     (float4 x 59,856)
  //   fdP  @ 311,296    (float4 x 59,856)
  //   tb   @ 550,912    (u32 x 19,952)
  //   zr   @ 570,880    (u32 x 8: [0..1]=min(0xFF) [2..3]=max(0) [4]=cursor(0))
  //   cnt  @ 571,008    (u32 x 512*257)
  //   list @ 702,720    (u16 x 1,800,000)
  float* nacc = ws;
  float4* fdE = (float4*)(ws + 71680);
  float4* fdP = (float4*)(ws + 311296);
  unsigned* tb = (unsigned*)(ws + 550912);
  unsigned* zr = (unsigned*)(ws + 570880);
  unsigned* cnt = (unsigned*)(ws + 571008);
  unsigned short* list = (unsigned short*)(ws + 702720);

  hipMemsetAsync(nacc, 0, (size_t)kB * kNV * 3 * sizeof(float), stream);
  hipMemsetAsync(zr, 0xFF, 2 * sizeof(unsigned), stream);       // zrMin
  hipMemsetAsync(zr + 2, 0x00, 3 * sizeof(unsigned), stream);   // zrMax+cursor

  hipLaunchKernelGGL(setup_k, dim3((kNF + 255) / 256, kB), dim3(256), 0,
                     stream, verts, faces, nacc, fdE, fdP, tb, zr);
  hipLaunchKernelGGL(bin_k, dim3(kChunks, 32, kB), dim3(256), 0,
                     stream, fdP, tb, zr, cnt, list);
  hipLaunchKernelGGL(raster_k, dim3(32, 32, kB), dim3(256), 0, stream,
                     fdP, fdE, cnt, list, zr, verts, nacc, faces, out);
}